// Round 10
// baseline (123.771 us; speedup 1.0000x reference)
//
#include <hip/hip_runtime.h>
#include <hip/hip_bf16.h>
#include <stdint.h>

// LinearEnsemble: out[b,m,o] = sum_i W[m,o,i]*x[b,i] + bias[m,o]
// == C[4096x8192] = x[4096x1024] * Wbig^T (+bias), Wbig = [8192x1024] row-major.
// v11: FUSED conversion. The separate f32->bf16 cvt pass (~12-14us serial, 72 MB
//     traffic) is folded into GEMM staging: global f32 loads at slice front ->
//     pack8 -> ds_write_b128 at slice tail (T14 issue-early/write-late).
//   - ring 4 -> 2 (reg staging needs only 1-slice lead); LDS 128->64 KB.
//   - counted-lgkm ladder (v10) unchanged: ds_writes drain via tail lgkmcnt(0)
//     before the barrier, so each slice's lgkm stream is a pure 12-read window.
//   - no manual vmcnt anywhere: f32 staging loads are compiler-tracked; its
//     precise waitcnt lands at the tail where data arrived ~2500 cyc earlier.
//   - granule involution swizzle (0-conflict, verified R2), XCD banding,
//     epilogue: unchanged from green v10.

typedef __bf16 bf16;
typedef __attribute__((ext_vector_type(8))) __bf16 bf16x8;
typedef __attribute__((ext_vector_type(4))) float f32x4;

#define LAS __attribute__((address_space(3)))

// raw barrier with compiler-level memory fence (no vmcnt/lgkm drain emitted)
__device__ __forceinline__ void wg_barrier() {
    asm volatile("" ::: "memory");
    __builtin_amdgcn_s_barrier();
    asm volatile("" ::: "memory");
}

#define LGKMCNT(n) asm volatile("s_waitcnt lgkmcnt(" #n ")" ::: "memory")
#define SCHED_FENCE() __builtin_amdgcn_sched_barrier(0)

// untracked LDS fragment read; ordering enforced by counted waits + SCHED_FENCE
template<int OFF>
__device__ __forceinline__ bf16x8 ds_read_frag(const char* p) {
    f32x4 r;
    asm volatile("ds_read_b128 %0, %1 offset:%2"
                 : "=v"(r)
                 : "v"((const LAS char*)p), "i"(OFF));
    return __builtin_bit_cast(bf16x8, r);
}

__device__ __forceinline__ uint4 pack8(float4 a, float4 b) {
    union { bf16 t[8]; uint4 v; } u;
    u.t[0] = (bf16)a.x; u.t[1] = (bf16)a.y; u.t[2] = (bf16)a.z; u.t[3] = (bf16)a.w;
    u.t[4] = (bf16)b.x; u.t[5] = (bf16)b.y; u.t[6] = (bf16)b.z; u.t[7] = (bf16)b.w;
    return u.v;
}

// ---------------- 256x256 fused-convert MFMA GEMM ----------------
// 512 threads = 8 waves (2 row x 4 col), wave owns 128x64 of C (8x4 frags of 16x16).
// LDS: ring of 2 K=32 slices, each = A[256][32] + B[256][32] bf16 = 32 KB -> 64 KB.
// Granule swizzle: stored pos s holds logical granule s ^ ((row>>1)&3); staging
// pre-swizzles the global SOURCE granule; reads apply the same XOR (involution).
__global__ __launch_bounds__(512, 2) void LE_gemm_f_kernel(const float* __restrict__ A,
                                                           const float* __restrict__ B,
                                                           const float* __restrict__ bias,
                                                           float* __restrict__ out) {
    constexpr int K  = 1024;
    constexpr int NS = 32;                 // K / 32 slices
    __shared__ bf16 As[2][256 * 32];       // 32 KB (slot stride 16384 B)
    __shared__ bf16 Bs[2][256 * 32];       // 32 KB

    // XCD band swizzle: 512 blocks, each XCD gets 16 row-tiles x 4 col-tiles.
    const int raw  = blockIdx.x;
    const int xcd  = raw & 7;
    const int idx  = raw >> 3;             // 0..63
    const int trow = idx >> 2;             // 0..15
    const int tcol = xcd * 4 + (idx & 3);  // 0..31

    const int tid  = threadIdx.x;
    const int lane = tid & 63;
    const int w    = tid >> 6;             // wave 0..7
    const int wr   = w >> 2, wc = w & 3;   // 2 x 4 wave grid
    const int fr   = lane & 15;
    const int fq   = lane >> 4;

    // staging: thread t covers 16 B (8 bf16 <- 8 f32) of row (t>>2) [+128 rows
    // for the 2nd write]; source granule pre-swizzled so the linear LDS write
    // realizes the XOR layout.
    const int sgran = ((tid & 3) ^ ((tid >> 3) & 3)) * 8;
    const float* a_srcf = A + (size_t)trow * 256 * K + (size_t)(tid >> 2) * K + sgran;
    const float* b_srcf = B + (size_t)tcol * 256 * K + (size_t)(tid >> 2) * K + sgran;

    // fragment-read bases (byte offsets within a slot), same XOR on granule
    const int rgran = (fq ^ ((fr >> 1) & 3)) * 8;
    const int aoff_b = ((wr * 128 + fr) * 32 + rgran) * 2;  // + mi*1024 imm, +4096 m-half1
    const int boff_b = ((wc * 64  + fr) * 32 + rgran) * 2;  // + ni*1024 imm
    const char* pab = (const char*)As + aoff_b;
    const char* pbb = (const char*)Bs + boff_b;

    f32x4 acc[8][4];
    const f32x4 zero = {0.f, 0.f, 0.f, 0.f};
#pragma unroll
    for (int mi = 0; mi < 8; ++mi)
#pragma unroll
        for (int ni = 0; ni < 4; ++ni) acc[mi][ni] = zero;

    // -------- prologue: load+convert+write slice 0 into slot 0 --------
    {
        float4 xa0 = *(const float4*)(a_srcf);
        float4 xa1 = *(const float4*)(a_srcf + 4);
        float4 xa2 = *(const float4*)(a_srcf + (size_t)128 * K);
        float4 xa3 = *(const float4*)(a_srcf + (size_t)128 * K + 4);
        float4 xb0 = *(const float4*)(b_srcf);
        float4 xb1 = *(const float4*)(b_srcf + 4);
        float4 xb2 = *(const float4*)(b_srcf + (size_t)128 * K);
        float4 xb3 = *(const float4*)(b_srcf + (size_t)128 * K + 4);
        char* da = (char*)As + tid * 16;
        char* db = (char*)Bs + tid * 16;
        *(uint4*)(da)        = pack8(xa0, xa1);
        *(uint4*)(da + 8192) = pack8(xa2, xa3);
        *(uint4*)(db)        = pack8(xb0, xb1);
        *(uint4*)(db + 8192) = pack8(xb2, xb3);
    }
    LGKMCNT(0);
    wg_barrier();

#define MFMA_QUAD(MI, AV)                                                              \
    acc[MI][0] = __builtin_amdgcn_mfma_f32_16x16x32_bf16(AV, bv0, acc[MI][0], 0, 0, 0); \
    acc[MI][1] = __builtin_amdgcn_mfma_f32_16x16x32_bf16(AV, bv1, acc[MI][1], 0, 0, 0); \
    acc[MI][2] = __builtin_amdgcn_mfma_f32_16x16x32_bf16(AV, bv2, acc[MI][2], 0, 0, 0); \
    acc[MI][3] = __builtin_amdgcn_mfma_f32_16x16x32_bf16(AV, bv3, acc[MI][3], 0, 0, 0)

#define DO_SLICE(S, JO)                                                                \
    {                                                                                  \
        constexpr int SOFF = (S) * 16384;                                              \
        constexpr int NOFF = ((S) ^ 1) * 16384;                                        \
        const int j = (JO) + (S);                                                      \
        /* front: B frags then m-half0 A frags (ladder counts on this order) */        \
        bf16x8 bv0 = ds_read_frag<SOFF + 0>(pbb);                                      \
        bf16x8 bv1 = ds_read_frag<SOFF + 1024>(pbb);                                   \
        bf16x8 bv2 = ds_read_frag<SOFF + 2048>(pbb);                                   \
        bf16x8 bv3 = ds_read_frag<SOFF + 3072>(pbb);                                   \
        bf16x8 af0 = ds_read_frag<SOFF + 0>(pab);                                      \
        bf16x8 af1 = ds_read_frag<SOFF + 1024>(pab);                                   \
        bf16x8 af2 = ds_read_frag<SOFF + 2048>(pab);                                   \
        bf16x8 af3 = ds_read_frag<SOFF + 3072>(pab);                                   \
        /* issue slice j+1's f32 staging loads (VMEM; invisible to lgkm ladder) */     \
        float4 xa0, xa1, xa2, xa3, xb0, xb1, xb2, xb3;                                 \
        if (j < NS - 1) {                                                              \
            const float* sa = a_srcf + (j + 1) * 32;                                   \
            const float* sb = b_srcf + (j + 1) * 32;                                   \
            xa0 = *(const float4*)(sa);                                                \
            xa1 = *(const float4*)(sa + 4);                                            \
            xa2 = *(const float4*)(sa + (size_t)128 * K);                              \
            xa3 = *(const float4*)(sa + (size_t)128 * K + 4);                          \
            xb0 = *(const float4*)(sb);                                                \
            xb1 = *(const float4*)(sb + 4);                                            \
            xb2 = *(const float4*)(sb + (size_t)128 * K);                              \
            xb3 = *(const float4*)(sb + (size_t)128 * K + 4);                          \
        }                                                                              \
        /* counted-lgkm ladder: each quad waits exactly its own A-frag (stream is */   \
        /* pure reads: last slice's writes drained by its tail lgkmcnt(0)).       */   \
        bf16x8 ag0, ag1, ag2, ag3;                                                     \
        LGKMCNT(3); SCHED_FENCE();     /* bv0..3 + af0 landed */                       \
        MFMA_QUAD(0, af0); ag0 = ds_read_frag<SOFF + 4096 + 0>(pab);                   \
        LGKMCNT(3); SCHED_FENCE();     /* af1 landed */                                \
        MFMA_QUAD(1, af1); ag1 = ds_read_frag<SOFF + 4096 + 1024>(pab);                \
        LGKMCNT(3); SCHED_FENCE();     /* af2 landed */                                \
        MFMA_QUAD(2, af2); ag2 = ds_read_frag<SOFF + 4096 + 2048>(pab);                \
        LGKMCNT(3); SCHED_FENCE();     /* af3 landed */                                \
        MFMA_QUAD(3, af3); ag3 = ds_read_frag<SOFF + 4096 + 3072>(pab);                \
        LGKMCNT(3); SCHED_FENCE();     /* ag0 landed */                                \
        MFMA_QUAD(4, ag0);                                                             \
        LGKMCNT(2); SCHED_FENCE();     /* ag1 landed */                                \
        MFMA_QUAD(5, ag1);                                                             \
        LGKMCNT(1); SCHED_FENCE();     /* ag2 landed */                                \
        MFMA_QUAD(6, ag2);                                                             \
        LGKMCNT(0); SCHED_FENCE();     /* ag3 landed */                                \
        MFMA_QUAD(7, ag3);                                                             \
        /* tail: convert + write slice j+1 into the other slot, drain, barrier.  */    \
        /* Writes target slot S^1; this slice's reads used slot S -> disjoint.   */    \
        if (j < NS - 1) {                                                              \
            char* da = (char*)As + NOFF + tid * 16;                                    \
            char* db = (char*)Bs + NOFF + tid * 16;                                    \
            *(uint4*)(da)        = pack8(xa0, xa1);                                    \
            *(uint4*)(da + 8192) = pack8(xa2, xa3);                                    \
            *(uint4*)(db)        = pack8(xb0, xb1);                                    \
            *(uint4*)(db + 8192) = pack8(xb2, xb3);                                    \
            LGKMCNT(0);            /* writes retired -> barrier globalizes */          \
            wg_barrier();                                                              \
        }                                                                              \
    }

    for (int jo = 0; jo < NS; jo += 2) {
        DO_SLICE(0, jo);
        DO_SLICE(1, jo);
    }
#undef DO_SLICE
#undef MFMA_QUAD

    // ---------------- epilogue: C = acc + bias[col] ----------------
    const int rowb = trow * 256 + wr * 128;
    const int colb = tcol * 256 + wc * 64;
    float bv[4];
#pragma unroll
    for (int fn = 0; fn < 4; ++fn) bv[fn] = bias[colb + fn * 16 + fr];
#pragma unroll
    for (int fm = 0; fm < 8; ++fm) {
        const int r0 = rowb + fm * 16 + fq * 4;
#pragma unroll
        for (int fn = 0; fn < 4; ++fn) {
            const int c = colb + fn * 16 + fr;
            float* p = out + (size_t)r0 * 8192 + c;
            f32x4 v = acc[fm][fn];
            p[0 * 8192] = v[0] + bv[fn];
            p[1 * 8192] = v[1] + bv[fn];
            p[2 * 8192] = v[2] + bv[fn];
            p[3 * 8192] = v[3] + bv[fn];
        }
    }
}

extern "C" void kernel_launch(void* const* d_in, const int* in_sizes, int n_in,
                              void* d_out, int out_size, void* d_ws, size_t ws_size,
                              hipStream_t stream) {
    const float* x    = (const float*)d_in[0];   // [4096, 1024]
    const float* wgt  = (const float*)d_in[1];   // [8, 1024, 1024] == Wbig^T [8192,1024]
    const float* bias = (const float*)d_in[2];   // [8, 1024] == [8192]
    float* out = (float*)d_out;                  // [4096, 8192]

    (void)d_ws; (void)ws_size; (void)in_sizes; (void)n_in; (void)out_size;
    LE_gemm_f_kernel<<<512, 512, 0, stream>>>(x, wgt, bias, out);
}

// Round 11
// 90.820 us; speedup vs baseline: 1.3628x; 1.3628x over previous
//
#include <hip/hip_runtime.h>
#include <hip/hip_bf16.h>
#include <stdint.h>

// LinearEnsemble: out[b,m,o] = sum_i W[m,o,i]*x[b,i] + bias[m,o]
// == C[4096x8192] = x[4096x1024] * Wbig^T (+bias), Wbig = [8192x1024] row-major.
// v12: faithful m201 8-phase port. cvt pass restored (v11 fusion reverted).
//   - BK=64 K-tiles, TWO alternating 1-K-tile LDS bufs (A 32K + B 32K each; 128 KB).
//   - 4 phases per K-tile (C-quadrant each): {ds-reads; stage 1 half-tile; BAR;
//     lgkmcnt(0); setprio(1); 16 MFMA; setprio(0); BAR}. Reads sit before the
//     barrier so DS drains during barrier convergence; MFMA cluster runs clean.
//   - staging spread: kt's 4 halves staged at (kt-2).P4 [same-buf, after reads
//     retired] and (kt-1).P1-P3 [other-buf]; guard = VMCNT(2) at each P4
//     (tail: VMCNT(0) at kt=14, none at 15).
//   - LDS swizzle for [128][64]-row layout: granule pos = (ks*4+fq)^(fr&7);
//     staging pre-swizzles the global source granule (both-sides involution).

typedef __bf16 bf16;
typedef __attribute__((ext_vector_type(8))) __bf16 bf16x8;
typedef __attribute__((ext_vector_type(4))) float f32x4;

#define GAS __attribute__((address_space(1)))
#define LAS __attribute__((address_space(3)))

__device__ __forceinline__ void gload_lds16(void* lds, const void* g) {
    __builtin_amdgcn_global_load_lds((const GAS uint32_t*)g, (LAS uint32_t*)lds, 16, 0, 0);
}

__device__ __forceinline__ void wg_barrier() {
    asm volatile("" ::: "memory");
    __builtin_amdgcn_s_barrier();
    asm volatile("" ::: "memory");
}

#define VMCNT(n)   asm volatile("s_waitcnt vmcnt(" #n ")" ::: "memory")
#define LGKM0      asm volatile("s_waitcnt lgkmcnt(0)" ::: "memory")
#define SCHED_FENCE() __builtin_amdgcn_sched_barrier(0)

template<int OFF>
__device__ __forceinline__ bf16x8 ds_read_frag(const char* p) {
    f32x4 r;
    asm volatile("ds_read_b128 %0, %1 offset:%2"
                 : "=v"(r)
                 : "v"((const LAS char*)p), "i"(OFF));
    return __builtin_bit_cast(bf16x8, r);
}

#define MFMA(A, B, C) __builtin_amdgcn_mfma_f32_16x16x32_bf16(A, B, C, 0, 0, 0)

__device__ __forceinline__ uint4 pack8(float4 a, float4 b) {
    union { bf16 t[8]; uint4 v; } u;
    u.t[0] = (bf16)a.x; u.t[1] = (bf16)a.y; u.t[2] = (bf16)a.z; u.t[3] = (bf16)a.w;
    u.t[4] = (bf16)b.x; u.t[5] = (bf16)b.y; u.t[6] = (bf16)b.z; u.t[7] = (bf16)b.w;
    return u.v;
}

// ---------------- fused f32 -> bf16 convert for x and W (one launch) ----------------
__global__ void LE_cvt2_kernel(const float* __restrict__ x, const float* __restrict__ w,
                               bf16* __restrict__ out, int nx, int ntot) {
    const int stride = gridDim.x * blockDim.x * 8;
    for (int i = (blockIdx.x * blockDim.x + threadIdx.x) * 8; i < ntot; i += stride) {
        const float* s = (i < nx) ? (x + i) : (w + (i - nx));
        float4 f0 = *(const float4*)s;
        float4 f1 = *(const float4*)(s + 4);
        *(uint4*)(out + i) = pack8(f0, f1);
    }
}

// ---------------- 256x256, BK=64, 8-phase (2 K-tiles/iter) MFMA GEMM ----------------
// 512 threads = 8 waves (2x4), wave owns 128x64 (8x4 frags of 16x16).
// LDS 128 KB: A[buf][half][128*64] at buf*32768 + half*16384;
//             B likewise at +65536. One K-tile per buf, bufs alternate per K-tile.
__global__ __launch_bounds__(512, 2) void LE_gemm_p8_kernel(const bf16* __restrict__ A,
                                                            const bf16* __restrict__ B,
                                                            const float* __restrict__ bias,
                                                            float* __restrict__ out) {
    constexpr int K  = 1024;
    constexpr int NT = 16;                 // K / 64 K-tiles
    __shared__ char Lc[131072];

    // XCD band swizzle: 512 blocks, each XCD gets 16 row-tiles x 4 col-tiles.
    const int raw  = blockIdx.x;
    const int xcd  = raw & 7;
    const int idx  = raw >> 3;
    const int trow = idx >> 2;             // 0..15
    const int tcol = xcd * 4 + (idx & 3);  // 0..31

    const int tid  = threadIdx.x;
    const int lane = tid & 63;
    const int w    = tid >> 6;
    const int wr   = w >> 2, wc = w & 3;   // 2 x 4 wave grid
    const int fr   = lane & 15;
    const int fq   = lane >> 4;

    // staging: thread t covers 16 B (granule t&7) of row t>>3 within a 64-row
    // half-tile chunk; source granule pre-swizzled: sg = (t&7)^(row&7).
    const int sg = ((tid & 7) ^ ((tid >> 3) & 7)) * 8;
    const bf16* a_srcb = A + (size_t)(trow * 256 + (tid >> 3)) * K + sg;
    const bf16* b_srcb = B + (size_t)(tcol * 256 + (tid >> 3)) * K + sg;

    // fragment-read pointers: row-local byte = row*128 + pos*16,
    // pos(ks,fq,fr) = (ks*4+fq)^(fr&7); pa0/pb0 = ks0, pa1/pb1 = ks1 (pos^4).
    const int pos0 = fq ^ (fr & 7);
    const int pos1 = pos0 ^ 4;
    const char* pa0 = Lc + wr * 16384 + fr * 128 + pos0 * 16;
    const char* pa1 = Lc + wr * 16384 + fr * 128 + pos1 * 16;
    const char* pb0 = Lc + 65536 + (wc >> 1) * 16384 + (wc & 1) * 8192 + fr * 128 + pos0 * 16;
    const char* pb1 = Lc + 65536 + (wc >> 1) * 16384 + (wc & 1) * 8192 + fr * 128 + pos1 * 16;

    f32x4 acc[8][4];
    const f32x4 zero = {0.f, 0.f, 0.f, 0.f};
#pragma unroll
    for (int mi = 0; mi < 8; ++mi)
#pragma unroll
        for (int ni = 0; ni < 4; ++ni) acc[mi][ni] = zero;

#define STAGE_A(D, H, KT) {                                                        \
        char* d0 = Lc + (D) * 32768 + (H) * 16384 + tid * 16;                      \
        const bf16* s = a_srcb + (size_t)((H) * 128) * K + (KT) * 64;              \
        gload_lds16(d0,        s);                                                 \
        gload_lds16(d0 + 8192, s + (size_t)64 * K); }
#define STAGE_B(D, H, KT) {                                                        \
        char* d0 = Lc + 65536 + (D) * 32768 + (H) * 16384 + tid * 16;              \
        const bf16* s = b_srcb + (size_t)((H) * 128) * K + (KT) * 64;              \
        gload_lds16(d0,        s);                                                 \
        gload_lds16(d0 + 8192, s + (size_t)64 * K); }

    // -------- prologue: kt0 all 4 halves + kt1 H1; land kt0; barrier --------
    STAGE_A(0, 0, 0); STAGE_A(0, 1, 0); STAGE_B(0, 0, 0); STAGE_B(0, 1, 0);
    STAGE_A(1, 0, 1);
    VMCNT(2);          // kt0 landed; kt1-H1 stays in flight
    wg_barrier();

#define M8(AC0, AC1, AR, BR)                                                       \
    acc[AC0][AC1 + 0] = MFMA(AR[0][0], BR[0][0], acc[AC0][AC1 + 0]);               \
    acc[AC0][AC1 + 1] = MFMA(AR[0][0], BR[1][0], acc[AC0][AC1 + 1]);

    // period = one K-tile (4 phases). D = buf (compile-time), KT runtime.
#define PERIOD(D, KT) {                                                            \
        constexpr int OA = (D) * 32768;                                            \
        constexpr int OB = (D) * 32768;                                            \
        bf16x8 aL[4][2], bL[2][2], aH[4][2], bH[2][2];                             \
        /* ---- P1: read A[mh0] (8) + B[nh0] (4); stage kt+1 Ah1; Q(0..3,0..1) */  \
        aL[0][0] = ds_read_frag<OA + 0>(pa0);                                      \
        aL[1][0] = ds_read_frag<OA + 2048>(pa0);                                   \
        aL[2][0] = ds_read_frag<OA + 4096>(pa0);                                   \
        aL[3][0] = ds_read_frag<OA + 6144>(pa0);                                   \
        aL[0][1] = ds_read_frag<OA + 0>(pa1);                                      \
        aL[1][1] = ds_read_frag<OA + 2048>(pa1);                                   \
        aL[2][1] = ds_read_frag<OA + 4096>(pa1);                                   \
        aL[3][1] = ds_read_frag<OA + 6144>(pa1);                                   \
        bL[0][0] = ds_read_frag<OB + 0>(pb0);                                      \
        bL[1][0] = ds_read_frag<OB + 2048>(pb0);                                   \
        bL[0][1] = ds_read_frag<OB + 0>(pb1);                                      \
        bL[1][1] = ds_read_frag<OB + 2048>(pb1);                                   \
        if ((KT) + 1 < NT) STAGE_A((D) ^ 1, 1, (KT) + 1);                          \
        wg_barrier(); LGKM0; SCHED_FENCE();                                        \
        __builtin_amdgcn_s_setprio(1);                                             \
        _Pragma("unroll")                                                          \
        for (int ks = 0; ks < 2; ++ks)                                             \
            _Pragma("unroll")                                                      \
            for (int mi = 0; mi < 4; ++mi)                                         \
                _Pragma("unroll")                                                  \
                for (int ni = 0; ni < 2; ++ni)                                     \
                    acc[mi][ni] = MFMA(aL[mi][ks], bL[ni][ks], acc[mi][ni]);       \
        __builtin_amdgcn_s_setprio(0);                                             \
        SCHED_FENCE(); wg_barrier();                                               \
        /* ---- P2: read B[nh1] (4); stage kt+1 Bh0; Q(0..3,2..3) (A reused) */    \
        bH[0][0] = ds_read_frag<OB + 4096>(pb0);                                   \
        bH[1][0] = ds_read_frag<OB + 6144>(pb0);                                   \
        bH[0][1] = ds_read_frag<OB + 4096>(pb1);                                   \
        bH[1][1] = ds_read_frag<OB + 6144>(pb1);                                   \
        if ((KT) + 1 < NT) STAGE_B((D) ^ 1, 0, (KT) + 1);                          \
        wg_barrier(); LGKM0; SCHED_FENCE();                                        \
        __builtin_amdgcn_s_setprio(1);                                             \
        _Pragma("unroll")                                                          \
        for (int ks = 0; ks < 2; ++ks)                                             \
            _Pragma("unroll")                                                      \
            for (int mi = 0; mi < 4; ++mi)                                         \
                _Pragma("unroll")                                                  \
                for (int ni = 0; ni < 2; ++ni)                                     \
                    acc[mi][2 + ni] = MFMA(aL[mi][ks], bH[ni][ks], acc[mi][2 + ni]); \
        __builtin_amdgcn_s_setprio(0);                                             \
        SCHED_FENCE(); wg_barrier();                                               \
        /* ---- P3: read A[mh1] (8); stage kt+1 Bh1; Q(4..7,2..3) (B reused) */    \
        aH[0][0] = ds_read_frag<OA + 8192 + 0>(pa0);                               \
        aH[1][0] = ds_read_frag<OA + 8192 + 2048>(pa0);                            \
        aH[2][0] = ds_read_frag<OA + 8192 + 4096>(pa0);                            \
        aH[3][0] = ds_read_frag<OA + 8192 + 6144>(pa0);                            \
        aH[0][1] = ds_read_frag<OA + 8192 + 0>(pa1);                               \
        aH[1][1] = ds_read_frag<OA + 8192 + 2048>(pa1);                            \
        aH[2][1] = ds_read_frag<OA + 8192 + 4096>(pa1);                            \
        aH[3][1] = ds_read_frag<OA + 8192 + 6144>(pa1);                            \
        if ((KT) + 1 < NT) STAGE_B((D) ^ 1, 1, (KT) + 1);                          \
        wg_barrier(); LGKM0; SCHED_FENCE();                                        \
        __builtin_amdgcn_s_setprio(1);                                             \
        _Pragma("unroll")                                                          \
        for (int ks = 0; ks < 2; ++ks)                                             \
            _Pragma("unroll")                                                      \
            for (int mi = 0; mi < 4; ++mi)                                         \
                _Pragma("unroll")                                                  \
                for (int ni = 0; ni < 2; ++ni)                                     \
                    acc[4 + mi][2 + ni] = MFMA(aH[mi][ks], bH[ni][ks], acc[4 + mi][2 + ni]); \
        __builtin_amdgcn_s_setprio(0);                                             \
        SCHED_FENCE(); wg_barrier();                                               \
        /* ---- P4: no reads; stage kt+2 Ah0 into THIS buf (reads retired at  */   \
        /*      P3's lgkm0, globalized by P3's closing barrier); Q(4..7,0..1) */   \
        if ((KT) + 2 < NT) STAGE_A((D), 0, (KT) + 2);                              \
        wg_barrier(); SCHED_FENCE();                                               \
        __builtin_amdgcn_s_setprio(1);                                             \
        _Pragma("unroll")                                                          \
        for (int ks = 0; ks < 2; ++ks)                                             \
            _Pragma("unroll")                                                      \
            for (int mi = 0; mi < 4; ++mi)                                         \
                _Pragma("unroll")                                                  \
                for (int ni = 0; ni < 2; ++ni)                                     \
                    acc[4 + mi][ni] = MFMA(aH[mi][ks], bL[ni][ks], acc[4 + mi][ni]); \
        __builtin_amdgcn_s_setprio(0);                                             \
        SCHED_FENCE();                                                             \
        /* guard kt+1's buf fully landed (leaves only kt+2-H1 in flight) */        \
        if ((KT) <= NT - 3)      { VMCNT(2); }                                     \
        else if ((KT) == NT - 2) { VMCNT(0); }                                     \
        wg_barrier();                                                              \
    }

    for (int kt = 0; kt < NT; kt += 2) {
        PERIOD(0, kt);
        PERIOD(1, kt + 1);
    }
#undef PERIOD
#undef M8
#undef STAGE_A
#undef STAGE_B

    // ---------------- epilogue: C = acc + bias[col] ----------------
    const int rowb = trow * 256 + wr * 128;
    const int colb = tcol * 256 + wc * 64;
    float bv[4];
#pragma unroll
    for (int fn = 0; fn < 4; ++fn) bv[fn] = bias[colb + fn * 16 + fr];
#pragma unroll
    for (int fm = 0; fm < 8; ++fm) {
        const int r0 = rowb + fm * 16 + fq * 4;
#pragma unroll
        for (int fn = 0; fn < 4; ++fn) {
            const int c = colb + fn * 16 + fr;
            float* p = out + (size_t)r0 * 8192 + c;
            f32x4 v = acc[fm][fn];
            p[0 * 8192] = v[0] + bv[fn];
            p[1 * 8192] = v[1] + bv[fn];
            p[2 * 8192] = v[2] + bv[fn];
            p[3 * 8192] = v[3] + bv[fn];
        }
    }
}

// ---------------- fallback (no workspace): reg-staged f32 128x128 GEMM ----------------
__global__ __launch_bounds__(256) void LE_gemm_fb_kernel(const float* __restrict__ A,
                                                         const float* __restrict__ B,
                                                         const float* __restrict__ bias,
                                                         float* __restrict__ out) {
    constexpr int K = 1024;
    __shared__ bf16 As[128 * 32];
    __shared__ bf16 Bs[128 * 32];

    const int raw  = blockIdx.x;
    const int xcd  = raw & 7;
    const int idx  = raw >> 3;
    const int trow = idx & 31;
    const int tcol = xcd * 8 + (idx >> 5);

    const int tid  = threadIdx.x;
    const int lane = tid & 63;
    const int w    = tid >> 6;
    const int wr   = w >> 1, wc = w & 1;
    const int fr   = lane & 15;
    const int fq   = lane >> 4;

    f32x4 acc[4][4];
    const f32x4 zero = {0.f, 0.f, 0.f, 0.f};
#pragma unroll
    for (int mi = 0; mi < 4; mi++)
#pragma unroll
        for (int ni = 0; ni < 4; ni++) acc[mi][ni] = zero;

    const float* Ap = A + (size_t)trow * 128 * K;
    const float* Bp = B + (size_t)tcol * 128 * K;
    const int sr = tid >> 1;
    const int sc = (tid & 1) * 16;
    for (int k0 = 0; k0 < K; k0 += 32) {
        const float* pa = Ap + (size_t)sr * K + k0 + sc;
        const float* pb = Bp + (size_t)sr * K + k0 + sc;
        float4 a0 = *(const float4*)(pa + 0);
        float4 a1 = *(const float4*)(pa + 4);
        float4 a2 = *(const float4*)(pa + 8);
        float4 a3 = *(const float4*)(pa + 12);
        float4 b0 = *(const float4*)(pb + 0);
        float4 b1 = *(const float4*)(pb + 4);
        float4 b2 = *(const float4*)(pb + 8);
        float4 b3 = *(const float4*)(pb + 12);
        __syncthreads();
        char* la = (char*)As + sr * 64 + sc * 2;
        char* lb = (char*)Bs + sr * 64 + sc * 2;
        *(uint4*)(la)      = pack8(a0, a1);
        *(uint4*)(la + 16) = pack8(a2, a3);
        *(uint4*)(lb)      = pack8(b0, b1);
        *(uint4*)(lb + 16) = pack8(b2, b3);
        __syncthreads();
        bf16x8 af[4], bfv2[4];
#pragma unroll
        for (int mi = 0; mi < 4; mi++)
            af[mi] = *(const bf16x8*)&As[(wr * 64 + mi * 16 + fr) * 32 + fq * 8];
#pragma unroll
        for (int ni = 0; ni < 4; ni++)
            bfv2[ni] = *(const bf16x8*)&Bs[(wc * 64 + ni * 16 + fr) * 32 + fq * 8];
#pragma unroll
        for (int mi = 0; mi < 4; mi++)
#pragma unroll
            for (int ni = 0; ni < 4; ni++)
                acc[mi][ni] = __builtin_amdgcn_mfma_f32_16x16x32_bf16(af[mi], bfv2[ni],
                                                                      acc[mi][ni], 0, 0, 0);
    }
    __syncthreads();

    const int rowb = trow * 128 + wr * 64;
    const int colb = tcol * 128 + wc * 64;
#pragma unroll
    for (int mi = 0; mi < 4; mi++) {
        const int r0 = rowb + mi * 16 + fq * 4;
#pragma unroll
        for (int ni = 0; ni < 4; ni++) {
            const int c = colb + ni * 16 + fr;
            const float bvv = bias[c];
            float* p = out + (size_t)r0 * 8192 + c;
            f32x4 v = acc[mi][ni];
            p[0 * 8192] = v[0] + bvv;
            p[1 * 8192] = v[1] + bvv;
            p[2 * 8192] = v[2] + bvv;
            p[3 * 8192] = v[3] + bvv;
        }
    }
}

extern "C" void kernel_launch(void* const* d_in, const int* in_sizes, int n_in,
                              void* d_out, int out_size, void* d_ws, size_t ws_size,
                              hipStream_t stream) {
    const float* x    = (const float*)d_in[0];   // [4096, 1024]
    const float* wgt  = (const float*)d_in[1];   // [8, 1024, 1024] == Wbig^T [8192,1024]
    const float* bias = (const float*)d_in[2];   // [8, 1024] == [8192]
    float* out = (float*)d_out;                  // [4096, 8192]

    const size_t NX = (size_t)4096 * 1024;
    const size_t NW = (size_t)8192 * 1024;

    if (ws_size >= (NX + NW) * sizeof(bf16)) {
        bf16* xb = (bf16*)d_ws;
        bf16* wb = xb + NX;
        LE_cvt2_kernel<<<2048, 256, 0, stream>>>(x, wgt, xb, (int)NX, (int)(NX + NW));
        LE_gemm_p8_kernel<<<512, 512, 0, stream>>>(xb, wb, bias, out);
    } else {
        LE_gemm_fb_kernel<<<2048, 256, 0, stream>>>(x, wgt, bias, out);
    }
}